// Round 1
// baseline (1573.510 us; speedup 1.0000x reference)
//
#include <hip/hip_runtime.h>
#include <hip/hip_bf16.h>
#include <math.h>

typedef __bf16 bf16_t;
typedef __bf16 bf16x8 __attribute__((ext_vector_type(8)));
typedef float f32x4 __attribute__((ext_vector_type(4)));

#define SCALE_F 0.08838834764831845f  // 1/sqrt(128)

// ---------------- fp32 -> bf16 convert (vectorized) ----------------
__global__ void k_convert(const float* __restrict__ in, bf16_t* __restrict__ out, int n) {
    int i = (blockIdx.x * 256 + threadIdx.x) * 4;
    if (i >= n) return;
    float4 f = *(const float4*)(in + i);
    out[i + 0] = (bf16_t)f.x;
    out[i + 1] = (bf16_t)f.y;
    out[i + 2] = (bf16_t)f.z;
    out[i + 3] = (bf16_t)f.w;
}

// ---------------- transpose + convert: w[K][N] -> wt[N][K] bf16 ----------------
__global__ void k_transpose(const float* __restrict__ w, bf16_t* __restrict__ wt, int K, int N) {
    __shared__ float tile[32][33];
    int n0 = blockIdx.x * 32, k0 = blockIdx.y * 32;
    int tx = threadIdx.x & 31, ty = threadIdx.x >> 5;  // 32x8
#pragma unroll
    for (int i = 0; i < 32; i += 8)
        tile[ty + i][tx] = w[(size_t)(k0 + ty + i) * N + (n0 + tx)];
    __syncthreads();
#pragma unroll
    for (int i = 0; i < 32; i += 8)
        wt[(size_t)(n0 + ty + i) * K + (k0 + tx)] = (bf16_t)tile[tx][ty + i];
}

// ---------------- rope tables: cos/sin[t][i], i in 0..63, freq index i&31 ----------------
__global__ void k_rope_tables(float* __restrict__ cosT, float* __restrict__ sinT) {
    int idx = blockIdx.x * 256 + threadIdx.x;  // t*64 + i
    int t = idx >> 6, i = idx & 63;
    float invf = powf(10000.f, -(float)(i & 31) / 32.f);
    float ang = (float)t * invf;
    float s, c;
    sincosf(ang, &s, &c);
    cosT[idx] = c;
    sinT[idx] = s;
}

// ---------------- row-wise rmsnorm, in-place bf16, fp32 gain ----------------
__global__ void k_rmsnorm(bf16_t* __restrict__ x, const float* __restrict__ g, int C) {
    bf16_t* p = x + (size_t)blockIdx.x * C;
    float ss = 0.f;
    for (int i = threadIdx.x; i < C; i += 256) {
        float v = (float)p[i];
        ss += v * v;
    }
#pragma unroll
    for (int m = 32; m; m >>= 1) ss += __shfl_xor(ss, m);
    __shared__ float red[4];
    if ((threadIdx.x & 63) == 0) red[threadIdx.x >> 6] = ss;
    __syncthreads();
    float tot = red[0] + red[1] + red[2] + red[3];
    float scale = rsqrtf(tot / (float)C + 1e-6f);
    for (int i = threadIdx.x; i < C; i += 256)
        p[i] = (bf16_t)((float)p[i] * scale * g[i]);
}

// ---------------- GEMM: C[M][N] = A[M][K] @ Bt[N][K]^T, bf16 in, fp32 acc ----------------
// 128x128 tile, BK=32, 4 waves in 2x2, each 64x64 via 4x4 mfma_f32_16x16x32_bf16.
// M must be mult of 128, K mult of 32. N guarded.
template <int OUTF32>
__global__ __launch_bounds__(256) void k_gemm(const bf16_t* __restrict__ A,
                                              const bf16_t* __restrict__ Bt,
                                              void* __restrict__ Cp, int M, int N, int K) {
    constexpr int LDK = 40;  // 32 + 8 pad (80B rows, 16B aligned)
    __shared__ bf16_t As[128 * LDK];
    __shared__ bf16_t Bs[128 * LDK];
    const int bm = blockIdx.y * 128, bn = blockIdx.x * 128;
    const int tid = threadIdx.x, lane = tid & 63, wv = tid >> 6;
    const int quad = lane >> 4, l16 = lane & 15;
    const int wm = (wv >> 1) * 64, wn = (wv & 1) * 64;
    f32x4 acc[4][4];
#pragma unroll
    for (int a = 0; a < 4; ++a)
#pragma unroll
        for (int b = 0; b < 4; ++b)
#pragma unroll
            for (int r = 0; r < 4; ++r) acc[a][b][r] = 0.f;
    const int ar = tid >> 2, ac = (tid & 3) * 8;
    for (int k0 = 0; k0 < K; k0 += 32) {
#pragma unroll
        for (int p = 0; p < 2; ++p) {
            int r = ar + p * 64;
            *(bf16x8*)(As + r * LDK + ac) = *(const bf16x8*)(A + (size_t)(bm + r) * K + k0 + ac);
            bf16x8 bv;
#pragma unroll
            for (int j = 0; j < 8; ++j) bv[j] = (bf16_t)0.f;
            if (bn + r < N) bv = *(const bf16x8*)(Bt + (size_t)(bn + r) * K + k0 + ac);
            *(bf16x8*)(Bs + r * LDK + ac) = bv;
        }
        __syncthreads();
        bf16x8 af[4], bfr[4];
#pragma unroll
        for (int mi = 0; mi < 4; ++mi)
            af[mi] = *(bf16x8*)(As + (wm + mi * 16 + l16) * LDK + quad * 8);
#pragma unroll
        for (int ni = 0; ni < 4; ++ni)
            bfr[ni] = *(bf16x8*)(Bs + (wn + ni * 16 + l16) * LDK + quad * 8);
#pragma unroll
        for (int mi = 0; mi < 4; ++mi)
#pragma unroll
            for (int ni = 0; ni < 4; ++ni)
                acc[mi][ni] =
                    __builtin_amdgcn_mfma_f32_16x16x32_bf16(af[mi], bfr[ni], acc[mi][ni], 0, 0, 0);
        __syncthreads();
    }
    // C/D layout: col = lane&15, row = quad*4 + r  [m89-verified]
#pragma unroll
    for (int mi = 0; mi < 4; ++mi)
#pragma unroll
        for (int ni = 0; ni < 4; ++ni)
#pragma unroll
            for (int r = 0; r < 4; ++r) {
                int row = bm + wm + mi * 16 + quad * 4 + r;
                int col = bn + wn + ni * 16 + l16;
                if (col < N) {
                    if constexpr (OUTF32)
                        ((float*)Cp)[(size_t)row * N + col] = acc[mi][ni][r];
                    else
                        ((bf16_t*)Cp)[(size_t)row * N + col] = (bf16_t)acc[mi][ni][r];
                }
            }
}

// ---------------- build q: in-place rope (upper 64) + rmsnorm(128) per (b,t,h) ----------------
// layout: q[(b*2048+t)*2048 + h*128 + d]. One wave per (row,h).
__global__ void k_build_q(bf16_t* __restrict__ q, const float* __restrict__ g,
                          const float* __restrict__ cosT, const float* __restrict__ sinT) {
    int wid = blockIdx.x * 4 + (threadIdx.x >> 6);
    int lane = threadIdx.x & 63;
    int row = wid >> 4, h = wid & 15;
    int t = row & 2047;
    bf16_t* p = q + (size_t)row * 2048 + h * 128;
    float x0 = (float)p[lane];
    float x1 = (float)p[64 + lane];
    float xp = (float)p[64 + (lane ^ 32)];
    float c = cosT[t * 64 + lane], s = sinT[t * 64 + lane];
    float rot = (lane < 32) ? -xp : xp;
    float y1 = x1 * c + rot * s;
    float ss = x0 * x0 + y1 * y1;
#pragma unroll
    for (int m = 32; m; m >>= 1) ss += __shfl_xor(ss, m);
    float scale = rsqrtf(ss / 128.f + 1e-6f);
    p[lane] = (bf16_t)(x0 * scale * g[lane]);
    p[64 + lane] = (bf16_t)(y1 * scale * g[64 + lane]);
}

// ---------------- build k: gather nope + roped shared rope part, rmsnorm, write (row,h*128+d) ----
__global__ void k_build_k(const bf16_t* __restrict__ knope, const bf16_t* __restrict__ krope,
                          bf16_t* __restrict__ kout, const float* __restrict__ g,
                          const float* __restrict__ cosT, const float* __restrict__ sinT) {
    int wid = blockIdx.x * 4 + (threadIdx.x >> 6);
    int lane = threadIdx.x & 63;
    int row = wid >> 4, h = wid & 15;
    int t = row & 2047;
    float x0 = (float)knope[(size_t)row * 1024 + h * 64 + lane];
    float x1 = (float)krope[(size_t)row * 64 + lane];
    float xp = (float)krope[(size_t)row * 64 + (lane ^ 32)];
    float c = cosT[t * 64 + lane], s = sinT[t * 64 + lane];
    float rot = (lane < 32) ? -xp : xp;
    float y1 = x1 * c + rot * s;
    float ss = x0 * x0 + y1 * y1;
#pragma unroll
    for (int m = 32; m; m >>= 1) ss += __shfl_xor(ss, m);
    float scale = rsqrtf(ss / 128.f + 1e-6f);
    bf16_t* p = kout + (size_t)row * 2048 + h * 128;
    p[lane] = (bf16_t)(x0 * scale * g[lane]);
    p[64 + lane] = (bf16_t)(y1 * scale * g[64 + lane]);
}

// ---------------- flash attention + silu(gate) epilogue ----------------
// grid (T/64, B*H). Block 256 = 4 waves; wave w owns q-rows [w*16, w*16+16).
// q,k,v,gate,o all in layout [(b*2048 + pos)*2048 + h*128 + d].
__global__ __launch_bounds__(256) void k_attn(const bf16_t* __restrict__ q,
                                              const bf16_t* __restrict__ k,
                                              const bf16_t* __restrict__ v,
                                              const bf16_t* __restrict__ gate,
                                              bf16_t* __restrict__ o) {
    __shared__ bf16_t Qs[64 * 136];   // [64 t][128 d +8]
    __shared__ bf16_t Ks[64 * 136];   // [64 s][128 d +8]
    __shared__ bf16_t Vt[128 * 72];   // [128 d][64 s +8]
    __shared__ bf16_t Ps[64 * 72];    // [64 t][64 s +8]
    const int qb = blockIdx.x, bh = blockIdx.y;
    const int b = bh >> 4, h = bh & 15;
    const int t0 = qb * 64;
    const int tid = threadIdx.x, lane = tid & 63, wv = tid >> 6;
    const int quad = lane >> 4, l16 = lane & 15;

    {   // stage Q once
        int r = tid >> 4, c = (tid & 15) * 8;
#pragma unroll
        for (int p = 0; p < 4; ++p)
            *(bf16x8*)(Qs + (r + p * 16) * 136 + c) =
                *(const bf16x8*)(q + ((size_t)(b * 2048 + t0 + r + p * 16)) * 2048 + h * 128 + c);
    }
    f32x4 oacc[8];
#pragma unroll
    for (int i = 0; i < 8; ++i)
#pragma unroll
        for (int r2 = 0; r2 < 4; ++r2) oacc[i][r2] = 0.f;
    float m_i[4], l_i[4];
#pragma unroll
    for (int r2 = 0; r2 < 4; ++r2) { m_i[r2] = -1e30f; l_i[r2] = 0.f; }

    const int nkb = qb + 1;  // causal: key blocks 0..qb
    for (int kb = 0; kb < nkb; ++kb) {
        const int s0 = kb * 64;
        __syncthreads();  // prev iter done reading Ks/Vt
        {
            int r = tid >> 4, c = (tid & 15) * 8;
#pragma unroll
            for (int p = 0; p < 4; ++p) {
                *(bf16x8*)(Ks + (r + p * 16) * 136 + c) =
                    *(const bf16x8*)(k + ((size_t)(b * 2048 + s0 + r + p * 16)) * 2048 + h * 128 + c);
                bf16x8 vv =
                    *(const bf16x8*)(v + ((size_t)(b * 2048 + s0 + r + p * 16)) * 2048 + h * 128 + c);
#pragma unroll
                for (int j = 0; j < 8; ++j) Vt[(c + j) * 72 + (r + p * 16)] = vv[j];
            }
        }
        __syncthreads();
        // S = Q K^T : wave's 16x64 strip, 4 n-tiles, k-dim = 128 (4 steps)
        f32x4 sc[4];
#pragma unroll
        for (int ni = 0; ni < 4; ++ni)
#pragma unroll
            for (int r2 = 0; r2 < 4; ++r2) sc[ni][r2] = 0.f;
#pragma unroll
        for (int kk = 0; kk < 4; ++kk) {
            bf16x8 aq = *(bf16x8*)(Qs + (wv * 16 + l16) * 136 + kk * 32 + quad * 8);
#pragma unroll
            for (int ni = 0; ni < 4; ++ni) {
                bf16x8 bk = *(bf16x8*)(Ks + (ni * 16 + l16) * 136 + kk * 32 + quad * 8);
                sc[ni] = __builtin_amdgcn_mfma_f32_16x16x32_bf16(aq, bk, sc[ni], 0, 0, 0);
            }
        }
        // scale + causal mask + online softmax (rows quad*4+r owned by 16-lane group)
        float rmax[4] = {-1e30f, -1e30f, -1e30f, -1e30f};
        const int trowb = t0 + wv * 16 + quad * 4;
#pragma unroll
        for (int ni = 0; ni < 4; ++ni) {
            int scol = s0 + ni * 16 + l16;
#pragma unroll
            for (int r2 = 0; r2 < 4; ++r2) {
                float val = sc[ni][r2] * SCALE_F;
                if (scol > trowb + r2) val = -1e30f;
                sc[ni][r2] = val;
                rmax[r2] = fmaxf(rmax[r2], val);
            }
        }
#pragma unroll
        for (int m = 8; m; m >>= 1)
#pragma unroll
            for (int r2 = 0; r2 < 4; ++r2) rmax[r2] = fmaxf(rmax[r2], __shfl_xor(rmax[r2], m));
        float alpha[4];
#pragma unroll
        for (int r2 = 0; r2 < 4; ++r2) {
            float mn = fmaxf(m_i[r2], rmax[r2]);
            alpha[r2] = __expf(m_i[r2] - mn);
            m_i[r2] = mn;
        }
        float rsum[4] = {0.f, 0.f, 0.f, 0.f};
#pragma unroll
        for (int ni = 0; ni < 4; ++ni)
#pragma unroll
            for (int r2 = 0; r2 < 4; ++r2) {
                float pv = __expf(sc[ni][r2] - m_i[r2]);
                sc[ni][r2] = pv;
                rsum[r2] += pv;
            }
#pragma unroll
        for (int m = 8; m; m >>= 1)
#pragma unroll
            for (int r2 = 0; r2 < 4; ++r2) rsum[r2] += __shfl_xor(rsum[r2], m);
#pragma unroll
        for (int r2 = 0; r2 < 4; ++r2) l_i[r2] = l_i[r2] * alpha[r2] + rsum[r2];
#pragma unroll
        for (int ni = 0; ni < 8; ++ni)
#pragma unroll
            for (int r2 = 0; r2 < 4; ++r2) oacc[ni][r2] *= alpha[r2];
        // P: C-layout -> LDS -> A-layout (wave-private strip, no barrier needed)
#pragma unroll
        for (int ni = 0; ni < 4; ++ni)
#pragma unroll
            for (int r2 = 0; r2 < 4; ++r2)
                Ps[(wv * 16 + quad * 4 + r2) * 72 + ni * 16 + l16] = (bf16_t)sc[ni][r2];
        // O += P V : k-dim = 64 keys (2 steps), 8 n-tiles of d
#pragma unroll
        for (int kk = 0; kk < 2; ++kk) {
            bf16x8 ap = *(bf16x8*)(Ps + (wv * 16 + l16) * 72 + kk * 32 + quad * 8);
#pragma unroll
            for (int ni = 0; ni < 8; ++ni) {
                bf16x8 bv = *(bf16x8*)(Vt + (ni * 16 + l16) * 72 + kk * 32 + quad * 8);
                oacc[ni] = __builtin_amdgcn_mfma_f32_16x16x32_bf16(ap, bv, oacc[ni], 0, 0, 0);
            }
        }
    }
    // epilogue: normalize, silu(gate), store
#pragma unroll
    for (int ni = 0; ni < 8; ++ni) {
        int d = ni * 16 + l16;
#pragma unroll
        for (int r2 = 0; r2 < 4; ++r2) {
            int trow = t0 + wv * 16 + quad * 4 + r2;
            size_t gi = ((size_t)(b * 2048 + trow)) * 2048 + h * 128 + d;
            float gt = (float)gate[gi];
            float sg = gt / (1.f + __expf(-gt));
            o[gi] = (bf16_t)((oacc[ni][r2] / l_i[r2]) * sg);
        }
    }
}

extern "C" void kernel_launch(void* const* d_in, const int* in_sizes, int n_in,
                              void* d_out, int out_size, void* d_ws, size_t ws_size,
                              hipStream_t stream) {
    const float* x         = (const float*)d_in[0];
    const float* w_q_down  = (const float*)d_in[1];
    const float* g_q_down  = (const float*)d_in[2];
    const float* w_q_up    = (const float*)d_in[3];
    const float* w_kv_down = (const float*)d_in[4];
    const float* g_kv_down = (const float*)d_in[5];
    const float* w_k_up    = (const float*)d_in[6];
    const float* w_v_up    = (const float*)d_in[7];
    const float* w_k_rope  = (const float*)d_in[8];
    const float* g_q       = (const float*)d_in[9];
    const float* g_k       = (const float*)d_in[10];
    const float* w_gate    = (const float*)d_in[11];
    const float* w_o       = (const float*)d_in[12];
    float* out = (float*)d_out;

    char* base = (char*)d_ws;
    size_t off = 0;
    auto alloc = [&](size_t bytes) -> void* {
        void* p = base + off;
        off = (off + bytes + 255) & ~(size_t)255;
        return p;
    };
    const size_t MT = 8192;  // B*T
    bf16_t* xb     = (bf16_t*)alloc(MT * 2048 * 2);
    bf16_t* wqd_t  = (bf16_t*)alloc((size_t)1024 * 2048 * 2);
    bf16_t* wqu_t  = (bf16_t*)alloc((size_t)2048 * 1024 * 2);
    bf16_t* wkvd_t = (bf16_t*)alloc((size_t)512 * 2048 * 2);
    bf16_t* wku_t  = (bf16_t*)alloc((size_t)1024 * 512 * 2);
    bf16_t* wvu_t  = (bf16_t*)alloc((size_t)2048 * 512 * 2);
    bf16_t* wkr_t  = (bf16_t*)alloc((size_t)64 * 2048 * 2);
    bf16_t* wg_t   = (bf16_t*)alloc((size_t)2048 * 2048 * 2);
    bf16_t* wo_t   = (bf16_t*)alloc((size_t)2048 * 2048 * 2);
    bf16_t* qc     = (bf16_t*)alloc(MT * 1024 * 2);
    bf16_t* ckv    = (bf16_t*)alloc(MT * 512 * 2);
    bf16_t* krope  = (bf16_t*)alloc(MT * 64 * 2);
    bf16_t* vbuf   = (bf16_t*)alloc(MT * 2048 * 2);
    bf16_t* gbuf   = (bf16_t*)alloc(MT * 2048 * 2);
    float* cosT    = (float*)alloc((size_t)2048 * 64 * 4);
    float* sinT    = (float*)alloc((size_t)2048 * 64 * 4);
    // aliases (lifetimes disjoint):
    bf16_t* knope = qc;                          // qc dead after q_up GEMM; knope written after
    bf16_t* qbuf  = (bf16_t*)d_out;              // d_out (67MB fp32) used as scratch until final GEMM
    bf16_t* kbuf  = (bf16_t*)d_out + MT * 2048;
    bf16_t* obuf  = xb;                          // xb dead once all x@W GEMMs done (before attn)

    // 1. convert x to bf16
    k_convert<<<dim3(16384), dim3(256), 0, stream>>>(x, xb, 16777216);
    // 2. weight transposes (w[K][N] -> wt[N][K]) ; grid (N/32, K/32)
    k_transpose<<<dim3(32, 64), 256, 0, stream>>>(w_q_down, wqd_t, 2048, 1024);
    k_transpose<<<dim3(64, 32), 256, 0, stream>>>(w_q_up, wqu_t, 1024, 2048);
    k_transpose<<<dim3(16, 64), 256, 0, stream>>>(w_kv_down, wkvd_t, 2048, 512);
    k_transpose<<<dim3(32, 16), 256, 0, stream>>>(w_k_up, wku_t, 512, 1024);
    k_transpose<<<dim3(64, 16), 256, 0, stream>>>(w_v_up, wvu_t, 512, 2048);
    k_transpose<<<dim3(2, 64), 256, 0, stream>>>(w_k_rope, wkr_t, 2048, 64);
    k_transpose<<<dim3(64, 64), 256, 0, stream>>>(w_gate, wg_t, 2048, 2048);
    k_transpose<<<dim3(64, 64), 256, 0, stream>>>(w_o, wo_t, 2048, 2048);
    // 3. rope tables
    k_rope_tables<<<dim3(512), 256, 0, stream>>>(cosT, sinT);
    // 4. q path
    k_gemm<0><<<dim3(8, 64), 256, 0, stream>>>(xb, wqd_t, qc, 8192, 1024, 2048);
    k_rmsnorm<<<dim3(8192), 256, 0, stream>>>(qc, g_q_down, 1024);
    k_gemm<0><<<dim3(16, 64), 256, 0, stream>>>(qc, wqu_t, qbuf, 8192, 2048, 1024);
    // 5. kv path
    k_gemm<0><<<dim3(4, 64), 256, 0, stream>>>(xb, wkvd_t, ckv, 8192, 512, 2048);
    k_rmsnorm<<<dim3(8192), 256, 0, stream>>>(ckv, g_kv_down, 512);
    k_gemm<0><<<dim3(8, 64), 256, 0, stream>>>(ckv, wku_t, knope, 8192, 1024, 512);
    k_gemm<0><<<dim3(16, 64), 256, 0, stream>>>(ckv, wvu_t, vbuf, 8192, 2048, 512);
    k_gemm<0><<<dim3(1, 64), 256, 0, stream>>>(xb, wkr_t, krope, 8192, 64, 2048);
    // 6. gate
    k_gemm<0><<<dim3(16, 64), 256, 0, stream>>>(xb, wg_t, gbuf, 8192, 2048, 2048);
    // 7. assemble q/k (rope + per-head rmsnorm)
    k_build_q<<<dim3(32768), 256, 0, stream>>>(qbuf, g_q, cosT, sinT);
    k_build_k<<<dim3(32768), 256, 0, stream>>>(knope, krope, kbuf, g_k, cosT, sinT);
    // 8. flash attention + silu(gate), writes obuf (= xb region)
    k_attn<<<dim3(32, 64), 256, 0, stream>>>(qbuf, kbuf, vbuf, gbuf, obuf);
    // 9. output projection, fp32 out
    k_gemm<1><<<dim3(16, 64), 256, 0, stream>>>(obuf, wo_t, out, 8192, 2048, 2048);
}

// Round 2
// 1038.132 us; speedup vs baseline: 1.5157x; 1.5157x over previous
//
#include <hip/hip_runtime.h>
#include <hip/hip_bf16.h>
#include <math.h>

typedef __bf16 bf16_t;
typedef __bf16 bf16x8 __attribute__((ext_vector_type(8)));
typedef float f32x4 __attribute__((ext_vector_type(4)));

#define SCALE_F 0.08838834764831845f  // 1/sqrt(128)

// async global->LDS, 16B per lane; LDS dest = wave-uniform base + lane*16
#define GLOAD_LDS16(gp, lp)                                              \
    __builtin_amdgcn_global_load_lds(                                    \
        (const __attribute__((address_space(1))) void*)(gp),             \
        (__attribute__((address_space(3))) void*)(lp), 16, 0, 0)

// ---------------- fp32 -> bf16 convert (vectorized) ----------------
__global__ void k_convert(const float* __restrict__ in, bf16_t* __restrict__ out, int n) {
    int i = (blockIdx.x * 256 + threadIdx.x) * 4;
    if (i >= n) return;
    float4 f = *(const float4*)(in + i);
    out[i + 0] = (bf16_t)f.x;
    out[i + 1] = (bf16_t)f.y;
    out[i + 2] = (bf16_t)f.z;
    out[i + 3] = (bf16_t)f.w;
}

// ---------------- transpose + convert: w[K][N] -> wt[N][K] bf16 ----------------
__global__ void k_transpose(const float* __restrict__ w, bf16_t* __restrict__ wt, int K, int N) {
    __shared__ float tile[32][33];
    int n0 = blockIdx.x * 32, k0 = blockIdx.y * 32;
    int tx = threadIdx.x & 31, ty = threadIdx.x >> 5;  // 32x8
#pragma unroll
    for (int i = 0; i < 32; i += 8)
        tile[ty + i][tx] = w[(size_t)(k0 + ty + i) * N + (n0 + tx)];
    __syncthreads();
#pragma unroll
    for (int i = 0; i < 32; i += 8)
        wt[(size_t)(n0 + ty + i) * K + (k0 + tx)] = (bf16_t)tile[tx][ty + i];
}

// ---------------- rope tables ----------------
__global__ void k_rope_tables(float* __restrict__ cosT, float* __restrict__ sinT) {
    int idx = blockIdx.x * 256 + threadIdx.x;  // t*64 + i
    int t = idx >> 6, i = idx & 63;
    float invf = powf(10000.f, -(float)(i & 31) / 32.f);
    float ang = (float)t * invf;
    float s, c;
    sincosf(ang, &s, &c);
    cosT[idx] = c;
    sinT[idx] = s;
}

// ---------------- row-wise rmsnorm, in-place bf16, fp32 gain ----------------
__global__ void k_rmsnorm(bf16_t* __restrict__ x, const float* __restrict__ g, int C) {
    bf16_t* p = x + (size_t)blockIdx.x * C;
    float ss = 0.f;
    for (int i = threadIdx.x; i < C; i += 256) {
        float v = (float)p[i];
        ss += v * v;
    }
#pragma unroll
    for (int m = 32; m; m >>= 1) ss += __shfl_xor(ss, m);
    __shared__ float red[4];
    if ((threadIdx.x & 63) == 0) red[threadIdx.x >> 6] = ss;
    __syncthreads();
    float tot = red[0] + red[1] + red[2] + red[3];
    float scale = rsqrtf(tot / (float)C + 1e-6f);
    for (int i = threadIdx.x; i < C; i += 256)
        p[i] = (bf16_t)((float)p[i] * scale * g[i]);
}

// ---------------- GEMM (m97 structure): C[M][N] = A[M][K] @ Bt[N][K]^T ----------------
// 128x128 tile, BK=32, unpadded LDS staged via global_load_lds width=16.
// grid.z batches: A += z*sA, Bt += z*sB, C += z*sC (element strides).
template <int OUTF32>
__global__ __launch_bounds__(256) void k_gemm(const bf16_t* __restrict__ A,
                                              const bf16_t* __restrict__ Bt,
                                              void* __restrict__ Cp, int M, int N, int K,
                                              size_t sA, size_t sB, size_t sC) {
    __shared__ bf16_t As[128 * 32];
    __shared__ bf16_t Bs[128 * 32];
    A += (size_t)blockIdx.z * sA;
    Bt += (size_t)blockIdx.z * sB;
    const size_t coff = (size_t)blockIdx.z * sC;
    const int bm = blockIdx.y * 128, bn = blockIdx.x * 128;
    const int tid = threadIdx.x, lane = tid & 63, wv = tid >> 6;
    const int quad = lane >> 4, l16 = lane & 15;
    const int wm = (wv >> 1) * 64, wn = (wv & 1) * 64;
    f32x4 acc[4][4] = {};
    // staging: wave wv owns 16-row chunks {2wv, 2wv+1}; lane i -> row i/4, col (i%4)*8
    const int sr0 = wv * 32 + (lane >> 2);  // row in tile for chunk 2wv
    const int scc = (lane & 3) * 8;
    bf16_t* ldsA0 = As + (wv * 2) * 512;  // chunk = 16 rows * 32 cols = 512 elems = 1KB
    bf16_t* ldsA1 = As + (wv * 2 + 1) * 512;
    bf16_t* ldsB0 = Bs + (wv * 2) * 512;
    bf16_t* ldsB1 = Bs + (wv * 2 + 1) * 512;
    const bool bok0 = (bn + sr0) < N;
    const bool bok1 = (bn + sr0 + 16) < N;
    for (int k0 = 0; k0 < K; k0 += 32) {
        const bf16_t* gA = A + (size_t)(bm + sr0) * K + k0 + scc;
        const bf16_t* gB = Bt + (size_t)(bn + sr0) * K + k0 + scc;
        GLOAD_LDS16(gA, ldsA0);
        GLOAD_LDS16(gA + (size_t)16 * K, ldsA1);
        if (bok0) GLOAD_LDS16(gB, ldsB0);
        if (bok1) GLOAD_LDS16(gB + (size_t)16 * K, ldsB1);
        __syncthreads();
        bf16x8 af[4], bfr[4];
#pragma unroll
        for (int mi = 0; mi < 4; ++mi)
            af[mi] = *(bf16x8*)(As + (wm + mi * 16 + l16) * 32 + quad * 8);
#pragma unroll
        for (int ni = 0; ni < 4; ++ni)
            bfr[ni] = *(bf16x8*)(Bs + (wn + ni * 16 + l16) * 32 + quad * 8);
#pragma unroll
        for (int mi = 0; mi < 4; ++mi)
#pragma unroll
            for (int ni = 0; ni < 4; ++ni)
                acc[mi][ni] =
                    __builtin_amdgcn_mfma_f32_16x16x32_bf16(af[mi], bfr[ni], acc[mi][ni], 0, 0, 0);
        __syncthreads();
    }
    // C/D layout: col = lane&15, row = quad*4 + r  [m89-verified]
#pragma unroll
    for (int mi = 0; mi < 4; ++mi)
#pragma unroll
        for (int ni = 0; ni < 4; ++ni)
#pragma unroll
            for (int r = 0; r < 4; ++r) {
                int row = bm + wm + mi * 16 + quad * 4 + r;
                int col = bn + wn + ni * 16 + l16;
                if (col < N) {
                    if constexpr (OUTF32)
                        ((float*)Cp)[coff + (size_t)row * N + col] = acc[mi][ni][r];
                    else
                        ((bf16_t*)Cp)[coff + (size_t)row * N + col] = (bf16_t)acc[mi][ni][r];
                }
            }
}

// ---------------- build q: in-place rope (upper 64) + rmsnorm(128) per (b,t,h) ----------------
__global__ void k_build_q(bf16_t* __restrict__ q, const float* __restrict__ g,
                          const float* __restrict__ cosT, const float* __restrict__ sinT) {
    int wid = blockIdx.x * 4 + (threadIdx.x >> 6);
    int lane = threadIdx.x & 63;
    int row = wid >> 4, h = wid & 15;
    int t = row & 2047;
    bf16_t* p = q + (size_t)row * 2048 + h * 128;
    float x0 = (float)p[lane];
    float x1 = (float)p[64 + lane];
    float xp = (float)p[64 + (lane ^ 32)];
    float c = cosT[t * 64 + lane], s = sinT[t * 64 + lane];
    float rot = (lane < 32) ? -xp : xp;
    float y1 = x1 * c + rot * s;
    float ss = x0 * x0 + y1 * y1;
#pragma unroll
    for (int m = 32; m; m >>= 1) ss += __shfl_xor(ss, m);
    float scale = rsqrtf(ss / 128.f + 1e-6f);
    p[lane] = (bf16_t)(x0 * scale * g[lane]);
    p[64 + lane] = (bf16_t)(y1 * scale * g[64 + lane]);
}

// ---------------- build k ----------------
__global__ void k_build_k(const bf16_t* __restrict__ knope, const bf16_t* __restrict__ krope,
                          bf16_t* __restrict__ kout, const float* __restrict__ g,
                          const float* __restrict__ cosT, const float* __restrict__ sinT) {
    int wid = blockIdx.x * 4 + (threadIdx.x >> 6);
    int lane = threadIdx.x & 63;
    int row = wid >> 4, h = wid & 15;
    int t = row & 2047;
    float x0 = (float)knope[(size_t)row * 1024 + h * 64 + lane];
    float x1 = (float)krope[(size_t)row * 64 + lane];
    float xp = (float)krope[(size_t)row * 64 + (lane ^ 32)];
    float c = cosT[t * 64 + lane], s = sinT[t * 64 + lane];
    float rot = (lane < 32) ? -xp : xp;
    float y1 = x1 * c + rot * s;
    float ss = x0 * x0 + y1 * y1;
#pragma unroll
    for (int m = 32; m; m >>= 1) ss += __shfl_xor(ss, m);
    float scale = rsqrtf(ss / 128.f + 1e-6f);
    bf16_t* p = kout + (size_t)row * 2048 + h * 128;
    p[lane] = (bf16_t)(x0 * scale * g[lane]);
    p[64 + lane] = (bf16_t)(y1 * scale * g[64 + lane]);
}

// ---------------- flash attention + silu(gate) epilogue ----------------
// grid (T/64, B*H), 4 waves; wave w owns q-rows [w*16, w*16+16).
// q,k,gate,o layout [(b*2048+pos)*2048 + h*128 + d]; vT layout [b][h*128+d][t].
__global__ __launch_bounds__(256) void k_attn(const bf16_t* __restrict__ q,
                                              const bf16_t* __restrict__ k,
                                              const bf16_t* __restrict__ vT,
                                              const bf16_t* __restrict__ gate,
                                              bf16_t* __restrict__ o) {
    __shared__ bf16_t Ks[64 * 136];  // [s][128 d +8]   17.4 KB
    __shared__ bf16_t Vt[128 * 72];  // [d][64 s +8]    18.4 KB
    __shared__ bf16_t Ps[64 * 72];   // [t][64 s +8]     9.2 KB
    const int qb = (int)gridDim.x - 1 - (int)blockIdx.x;  // long blocks first
    const int bh = blockIdx.y;
    const int b = bh >> 4, h = bh & 15;
    const int t0 = qb * 64;
    const int tid = threadIdx.x, lane = tid & 63, wv = tid >> 6;
    const int quad = lane >> 4, l16 = lane & 15;

    // Q fragments in registers for the whole kernel (A-layout: m=l16, k=quad*8+j)
    bf16x8 aq[4];
    {
        const bf16_t* qp =
            q + ((size_t)(b * 2048 + t0 + wv * 16 + l16)) * 2048 + h * 128 + quad * 8;
#pragma unroll
        for (int kk = 0; kk < 4; ++kk) aq[kk] = *(const bf16x8*)(qp + kk * 32);
    }
    f32x4 oacc[8] = {};
    float m_i[4], l_i[4];
#pragma unroll
    for (int r2 = 0; r2 < 4; ++r2) { m_i[r2] = -1e30f; l_i[r2] = 0.f; }

    const bf16_t* vbase = vT + (size_t)b * 2048 * 2048 + (size_t)h * 128 * 2048;

    for (int kb = 0; kb <= qb; ++kb) {
        const int s0 = kb * 64;
        __syncthreads();  // prev iter done reading Ks/Vt
#pragma unroll
        for (int p = 0; p < 4; ++p) {  // stage K (64x128) and Vt (128x64), all b128
            int j = tid + p * 256;
            int kr = j >> 4, kc = (j & 15) * 8;
            *(bf16x8*)(Ks + kr * 136 + kc) =
                *(const bf16x8*)(k + ((size_t)(b * 2048 + s0 + kr)) * 2048 + h * 128 + kc);
            int vr = j >> 3, vc = (j & 7) * 8;
            *(bf16x8*)(Vt + vr * 72 + vc) =
                *(const bf16x8*)(vbase + (size_t)vr * 2048 + s0 + vc);
        }
        __syncthreads();
        // S = Q K^T : wave's 16x64 strip
        f32x4 sc[4] = {};
#pragma unroll
        for (int kk = 0; kk < 4; ++kk)
#pragma unroll
            for (int ni = 0; ni < 4; ++ni) {
                bf16x8 bk = *(bf16x8*)(Ks + (ni * 16 + l16) * 136 + kk * 32 + quad * 8);
                sc[ni] = __builtin_amdgcn_mfma_f32_16x16x32_bf16(aq[kk], bk, sc[ni], 0, 0, 0);
            }
        // scale + (diagonal-only) causal mask + online softmax
        const bool diag = (kb == qb);
        const int trowb = t0 + wv * 16 + quad * 4;
        float rmax[4] = {-1e30f, -1e30f, -1e30f, -1e30f};
#pragma unroll
        for (int ni = 0; ni < 4; ++ni) {
            int scol = s0 + ni * 16 + l16;
#pragma unroll
            for (int r2 = 0; r2 < 4; ++r2) {
                float val = sc[ni][r2] * SCALE_F;
                if (diag && scol > trowb + r2) val = -1e30f;
                sc[ni][r2] = val;
                rmax[r2] = fmaxf(rmax[r2], val);
            }
        }
#pragma unroll
        for (int m = 8; m; m >>= 1)
#pragma unroll
            for (int r2 = 0; r2 < 4; ++r2) rmax[r2] = fmaxf(rmax[r2], __shfl_xor(rmax[r2], m));
        float alpha[4];
#pragma unroll
        for (int r2 = 0; r2 < 4; ++r2) {
            float mn = fmaxf(m_i[r2], rmax[r2]);
            alpha[r2] = __expf(m_i[r2] - mn);
            m_i[r2] = mn;
        }
        float rsum[4] = {0.f, 0.f, 0.f, 0.f};
#pragma unroll
        for (int ni = 0; ni < 4; ++ni)
#pragma unroll
            for (int r2 = 0; r2 < 4; ++r2) {
                float pv = __expf(sc[ni][r2] - m_i[r2]);
                sc[ni][r2] = pv;
                rsum[r2] += pv;
            }
#pragma unroll
        for (int m = 8; m; m >>= 1)
#pragma unroll
            for (int r2 = 0; r2 < 4; ++r2) rsum[r2] += __shfl_xor(rsum[r2], m);
#pragma unroll
        for (int r2 = 0; r2 < 4; ++r2) l_i[r2] = l_i[r2] * alpha[r2] + rsum[r2];
#pragma unroll
        for (int ni = 0; ni < 8; ++ni)
#pragma unroll
            for (int r2 = 0; r2 < 4; ++r2) oacc[ni][r2] *= alpha[r2];
        // P: C-layout -> LDS -> A-layout (wave-private rows, no barrier needed)
#pragma unroll
        for (int ni = 0; ni < 4; ++ni)
#pragma unroll
            for (int r2 = 0; r2 < 4; ++r2)
                Ps[(wv * 16 + quad * 4 + r2) * 72 + ni * 16 + l16] = (bf16_t)sc[ni][r2];
        // O += P V
#pragma unroll
        for (int kk = 0; kk < 2; ++kk) {
            bf16x8 ap = *(bf16x8*)(Ps + (wv * 16 + l16) * 72 + kk * 32 + quad * 8);
#pragma unroll
            for (int ni = 0; ni < 8; ++ni) {
                bf16x8 bv = *(bf16x8*)(Vt + (ni * 16 + l16) * 72 + kk * 32 + quad * 8);
                oacc[ni] = __builtin_amdgcn_mfma_f32_16x16x32_bf16(ap, bv, oacc[ni], 0, 0, 0);
            }
        }
    }
    // epilogue: normalize, silu(gate), store
#pragma unroll
    for (int ni = 0; ni < 8; ++ni) {
        int d = ni * 16 + l16;
#pragma unroll
        for (int r2 = 0; r2 < 4; ++r2) {
            int trow = t0 + wv * 16 + quad * 4 + r2;
            size_t gi = ((size_t)(b * 2048 + trow)) * 2048 + h * 128 + d;
            float gt = (float)gate[gi];
            float sg = gt / (1.f + __expf(-gt));
            o[gi] = (bf16_t)((oacc[ni][r2] / l_i[r2]) * sg);
        }
    }
}

extern "C" void kernel_launch(void* const* d_in, const int* in_sizes, int n_in,
                              void* d_out, int out_size, void* d_ws, size_t ws_size,
                              hipStream_t stream) {
    const float* x         = (const float*)d_in[0];
    const float* w_q_down  = (const float*)d_in[1];
    const float* g_q_down  = (const float*)d_in[2];
    const float* w_q_up    = (const float*)d_in[3];
    const float* w_kv_down = (const float*)d_in[4];
    const float* g_kv_down = (const float*)d_in[5];
    const float* w_k_up    = (const float*)d_in[6];
    const float* w_v_up    = (const float*)d_in[7];
    const float* w_k_rope  = (const float*)d_in[8];
    const float* g_q       = (const float*)d_in[9];
    const float* g_k       = (const float*)d_in[10];
    const float* w_gate    = (const float*)d_in[11];
    const float* w_o       = (const float*)d_in[12];
    float* out = (float*)d_out;

    char* base = (char*)d_ws;
    size_t off = 0;
    auto alloc = [&](size_t bytes) -> void* {
        void* p = base + off;
        off = (off + bytes + 255) & ~(size_t)255;
        return p;
    };
    const size_t MT = 8192;  // B*T
    bf16_t* xb     = (bf16_t*)alloc(MT * 2048 * 2);
    bf16_t* wqd_t  = (bf16_t*)alloc((size_t)1024 * 2048 * 2);
    bf16_t* wqu_t  = (bf16_t*)alloc((size_t)2048 * 1024 * 2);
    bf16_t* wkvd_t = (bf16_t*)alloc((size_t)512 * 2048 * 2);
    bf16_t* wku_t  = (bf16_t*)alloc((size_t)1024 * 512 * 2);
    bf16_t* wvu_t  = (bf16_t*)alloc((size_t)2048 * 512 * 2);
    bf16_t* wkr_t  = (bf16_t*)alloc((size_t)64 * 2048 * 2);
    bf16_t* wg_t   = (bf16_t*)alloc((size_t)2048 * 2048 * 2);
    bf16_t* wo_t   = (bf16_t*)alloc((size_t)2048 * 2048 * 2);
    bf16_t* qc     = (bf16_t*)alloc(MT * 1024 * 2);
    bf16_t* ckv    = (bf16_t*)alloc(MT * 512 * 2);
    bf16_t* krope  = (bf16_t*)alloc(MT * 64 * 2);
    bf16_t* vT     = (bf16_t*)alloc(MT * 2048 * 2);  // [b][h*128+d][t]
    bf16_t* gbuf   = (bf16_t*)alloc(MT * 2048 * 2);
    float* cosT    = (float*)alloc((size_t)2048 * 64 * 4);
    float* sinT    = (float*)alloc((size_t)2048 * 64 * 4);
    // aliases (lifetimes disjoint):
    bf16_t* knope = qc;              // qc dead after q_up GEMM
    bf16_t* qbuf  = (bf16_t*)d_out;  // d_out used as scratch until final GEMM
    bf16_t* kbuf  = (bf16_t*)d_out + MT * 2048;
    bf16_t* obuf  = xb;              // xb dead after all x@W GEMMs

    k_convert<<<dim3(16384), dim3(256), 0, stream>>>(x, xb, 16777216);
    k_transpose<<<dim3(32, 64), 256, 0, stream>>>(w_q_down, wqd_t, 2048, 1024);
    k_transpose<<<dim3(64, 32), 256, 0, stream>>>(w_q_up, wqu_t, 1024, 2048);
    k_transpose<<<dim3(16, 64), 256, 0, stream>>>(w_kv_down, wkvd_t, 2048, 512);
    k_transpose<<<dim3(32, 16), 256, 0, stream>>>(w_k_up, wku_t, 512, 1024);
    k_transpose<<<dim3(64, 16), 256, 0, stream>>>(w_v_up, wvu_t, 512, 2048);
    k_transpose<<<dim3(2, 64), 256, 0, stream>>>(w_k_rope, wkr_t, 2048, 64);
    k_transpose<<<dim3(64, 64), 256, 0, stream>>>(w_gate, wg_t, 2048, 2048);
    k_transpose<<<dim3(64, 64), 256, 0, stream>>>(w_o, wo_t, 2048, 2048);
    k_rope_tables<<<dim3(512), 256, 0, stream>>>(cosT, sinT);
    // q path
    k_gemm<0><<<dim3(8, 64), 256, 0, stream>>>(xb, wqd_t, qc, 8192, 1024, 2048, 0, 0, 0);
    k_rmsnorm<<<dim3(8192), 256, 0, stream>>>(qc, g_q_down, 1024);
    k_gemm<0><<<dim3(16, 64), 256, 0, stream>>>(qc, wqu_t, qbuf, 8192, 2048, 1024, 0, 0, 0);
    // kv path
    k_gemm<0><<<dim3(4, 64), 256, 0, stream>>>(xb, wkvd_t, ckv, 8192, 512, 2048, 0, 0, 0);
    k_rmsnorm<<<dim3(8192), 256, 0, stream>>>(ckv, g_kv_down, 512);
    k_gemm<0><<<dim3(8, 64), 256, 0, stream>>>(ckv, wku_t, knope, 8192, 1024, 512, 0, 0, 0);
    // V^T per batch: vT_b[hd][t] = wvu_t[hd][k] · ckv_b[t][k]
    k_gemm<0><<<dim3(16, 16, 4), 256, 0, stream>>>(wvu_t, ckv, vT, 2048, 2048, 512,
                                                   0, (size_t)2048 * 512, (size_t)2048 * 2048);
    k_gemm<0><<<dim3(1, 64), 256, 0, stream>>>(xb, wkr_t, krope, 8192, 64, 2048, 0, 0, 0);
    // gate
    k_gemm<0><<<dim3(16, 64), 256, 0, stream>>>(xb, wg_t, gbuf, 8192, 2048, 2048, 0, 0, 0);
    // assemble q/k
    k_build_q<<<dim3(32768), 256, 0, stream>>>(qbuf, g_q, cosT, sinT);
    k_build_k<<<dim3(32768), 256, 0, stream>>>(knope, krope, kbuf, g_k, cosT, sinT);
    // attention + silu(gate)
    k_attn<<<dim3(32, 64), 256, 0, stream>>>(qbuf, kbuf, vT, gbuf, obuf);
    // output projection
    k_gemm<1><<<dim3(16, 64), 256, 0, stream>>>(obuf, wo_t, out, 8192, 2048, 2048, 0, 0, 0);
}

// Round 3
// 845.069 us; speedup vs baseline: 1.8620x; 1.2285x over previous
//
#include <hip/hip_runtime.h>
#include <hip/hip_bf16.h>
#include <math.h>

typedef __bf16 bf16_t;
typedef __bf16 bf16x8 __attribute__((ext_vector_type(8)));
typedef float f32x4 __attribute__((ext_vector_type(4)));

#define SCALE_F 0.08838834764831845f  // 1/sqrt(128)
#define SMAX_F 14.0f                  // fixed softmax max: score <= sqrt(128)=11.32 (+bf16 margin)

// async global->LDS, 16B per lane; LDS dest = wave-uniform base + lane*16
#define GLOAD_LDS16(gp, lp)                                              \
    __builtin_amdgcn_global_load_lds(                                    \
        (const __attribute__((address_space(1))) void*)(gp),             \
        (__attribute__((address_space(3))) void*)(lp), 16, 0, 0)

// ---------------- fp32 -> bf16 convert (vectorized) ----------------
__global__ void k_convert(const float* __restrict__ in, bf16_t* __restrict__ out, int n) {
    int i = (blockIdx.x * 256 + threadIdx.x) * 4;
    if (i >= n) return;
    float4 f = *(const float4*)(in + i);
    out[i + 0] = (bf16_t)f.x;
    out[i + 1] = (bf16_t)f.y;
    out[i + 2] = (bf16_t)f.z;
    out[i + 3] = (bf16_t)f.w;
}

// ---------------- transpose + convert: w[K][N] -> wt[N][K] bf16 ----------------
__global__ void k_transpose(const float* __restrict__ w, bf16_t* __restrict__ wt, int K, int N) {
    __shared__ float tile[32][33];
    int n0 = blockIdx.x * 32, k0 = blockIdx.y * 32;
    int tx = threadIdx.x & 31, ty = threadIdx.x >> 5;  // 32x8
#pragma unroll
    for (int i = 0; i < 32; i += 8)
        tile[ty + i][tx] = w[(size_t)(k0 + ty + i) * N + (n0 + tx)];
    __syncthreads();
#pragma unroll
    for (int i = 0; i < 32; i += 8)
        wt[(size_t)(n0 + ty + i) * K + (k0 + tx)] = (bf16_t)tile[tx][ty + i];
}

// ---------------- rope tables ----------------
__global__ void k_rope_tables(float* __restrict__ cosT, float* __restrict__ sinT) {
    int idx = blockIdx.x * 256 + threadIdx.x;  // t*64 + i
    int t = idx >> 6, i = idx & 63;
    float invf = powf(10000.f, -(float)(i & 31) / 32.f);
    float ang = (float)t * invf;
    float s, c;
    sincosf(ang, &s, &c);
    cosT[idx] = c;
    sinT[idx] = s;
}

// ---------------- row-wise rmsnorm, in-place bf16, fp32 gain ----------------
__global__ void k_rmsnorm(bf16_t* __restrict__ x, const float* __restrict__ g, int C) {
    bf16_t* p = x + (size_t)blockIdx.x * C;
    float ss = 0.f;
    for (int i = threadIdx.x; i < C; i += 256) {
        float v = (float)p[i];
        ss += v * v;
    }
#pragma unroll
    for (int m = 32; m; m >>= 1) ss += __shfl_xor(ss, m);
    __shared__ float red[4];
    if ((threadIdx.x & 63) == 0) red[threadIdx.x >> 6] = ss;
    __syncthreads();
    float tot = red[0] + red[1] + red[2] + red[3];
    float scale = rsqrtf(tot / (float)C + 1e-6f);
    for (int i = threadIdx.x; i < C; i += 256)
        p[i] = (bf16_t)((float)p[i] * scale * g[i]);
}

// ---------------- GEMM (m97 structure): C[M][N] = A[M][K] @ Bt[N][K]^T ----------------
template <int OUTF32>
__global__ __launch_bounds__(256) void k_gemm(const bf16_t* __restrict__ A,
                                              const bf16_t* __restrict__ Bt,
                                              void* __restrict__ Cp, int M, int N, int K,
                                              size_t sA, size_t sB, size_t sC) {
    __shared__ bf16_t As[128 * 32];
    __shared__ bf16_t Bs[128 * 32];
    A += (size_t)blockIdx.z * sA;
    Bt += (size_t)blockIdx.z * sB;
    const size_t coff = (size_t)blockIdx.z * sC;
    const int bm = blockIdx.y * 128, bn = blockIdx.x * 128;
    const int tid = threadIdx.x, lane = tid & 63, wv = tid >> 6;
    const int quad = lane >> 4, l16 = lane & 15;
    const int wm = (wv >> 1) * 64, wn = (wv & 1) * 64;
    f32x4 acc[4][4] = {};
    const int sr0 = wv * 32 + (lane >> 2);
    const int scc = (lane & 3) * 8;
    bf16_t* ldsA0 = As + (wv * 2) * 512;
    bf16_t* ldsA1 = As + (wv * 2 + 1) * 512;
    bf16_t* ldsB0 = Bs + (wv * 2) * 512;
    bf16_t* ldsB1 = Bs + (wv * 2 + 1) * 512;
    const bool bok0 = (bn + sr0) < N;
    const bool bok1 = (bn + sr0 + 16) < N;
    for (int k0 = 0; k0 < K; k0 += 32) {
        const bf16_t* gA = A + (size_t)(bm + sr0) * K + k0 + scc;
        const bf16_t* gB = Bt + (size_t)(bn + sr0) * K + k0 + scc;
        GLOAD_LDS16(gA, ldsA0);
        GLOAD_LDS16(gA + (size_t)16 * K, ldsA1);
        if (bok0) GLOAD_LDS16(gB, ldsB0);
        if (bok1) GLOAD_LDS16(gB + (size_t)16 * K, ldsB1);
        __syncthreads();
        bf16x8 af[4], bfr[4];
#pragma unroll
        for (int mi = 0; mi < 4; ++mi)
            af[mi] = *(bf16x8*)(As + (wm + mi * 16 + l16) * 32 + quad * 8);
#pragma unroll
        for (int ni = 0; ni < 4; ++ni)
            bfr[ni] = *(bf16x8*)(Bs + (wn + ni * 16 + l16) * 32 + quad * 8);
#pragma unroll
        for (int mi = 0; mi < 4; ++mi)
#pragma unroll
            for (int ni = 0; ni < 4; ++ni)
                acc[mi][ni] =
                    __builtin_amdgcn_mfma_f32_16x16x32_bf16(af[mi], bfr[ni], acc[mi][ni], 0, 0, 0);
        __syncthreads();
    }
#pragma unroll
    for (int mi = 0; mi < 4; ++mi)
#pragma unroll
        for (int ni = 0; ni < 4; ++ni)
#pragma unroll
            for (int r = 0; r < 4; ++r) {
                int row = bm + wm + mi * 16 + quad * 4 + r;
                int col = bn + wn + ni * 16 + l16;
                if (col < N) {
                    if constexpr (OUTF32)
                        ((float*)Cp)[coff + (size_t)row * N + col] = acc[mi][ni][r];
                    else
                        ((bf16_t*)Cp)[coff + (size_t)row * N + col] = (bf16_t)acc[mi][ni][r];
                }
            }
}

// ---------------- build q ----------------
__global__ void k_build_q(bf16_t* __restrict__ q, const float* __restrict__ g,
                          const float* __restrict__ cosT, const float* __restrict__ sinT) {
    int wid = blockIdx.x * 4 + (threadIdx.x >> 6);
    int lane = threadIdx.x & 63;
    int row = wid >> 4, h = wid & 15;
    int t = row & 2047;
    bf16_t* p = q + (size_t)row * 2048 + h * 128;
    float x0 = (float)p[lane];
    float x1 = (float)p[64 + lane];
    float xp = (float)p[64 + (lane ^ 32)];
    float c = cosT[t * 64 + lane], s = sinT[t * 64 + lane];
    float rot = (lane < 32) ? -xp : xp;
    float y1 = x1 * c + rot * s;
    float ss = x0 * x0 + y1 * y1;
#pragma unroll
    for (int m = 32; m; m >>= 1) ss += __shfl_xor(ss, m);
    float scale = rsqrtf(ss / 128.f + 1e-6f);
    p[lane] = (bf16_t)(x0 * scale * g[lane]);
    p[64 + lane] = (bf16_t)(y1 * scale * g[64 + lane]);
}

// ---------------- build k ----------------
__global__ void k_build_k(const bf16_t* __restrict__ knope, const bf16_t* __restrict__ krope,
                          bf16_t* __restrict__ kout, const float* __restrict__ g,
                          const float* __restrict__ cosT, const float* __restrict__ sinT) {
    int wid = blockIdx.x * 4 + (threadIdx.x >> 6);
    int lane = threadIdx.x & 63;
    int row = wid >> 4, h = wid & 15;
    int t = row & 2047;
    float x0 = (float)knope[(size_t)row * 1024 + h * 64 + lane];
    float x1 = (float)krope[(size_t)row * 64 + lane];
    float xp = (float)krope[(size_t)row * 64 + (lane ^ 32)];
    float c = cosT[t * 64 + lane], s = sinT[t * 64 + lane];
    float rot = (lane < 32) ? -xp : xp;
    float y1 = x1 * c + rot * s;
    float ss = x0 * x0 + y1 * y1;
#pragma unroll
    for (int m = 32; m; m >>= 1) ss += __shfl_xor(ss, m);
    float scale = rsqrtf(ss / 128.f + 1e-6f);
    bf16_t* p = kout + (size_t)row * 2048 + h * 128;
    p[lane] = (bf16_t)(x0 * scale * g[lane]);
    p[64 + lane] = (bf16_t)(y1 * scale * g[64 + lane]);
}

// ---------------- flash attention + silu(gate), fixed-max softmax ----------------
// grid (T/128, B*H), 512 threads = 8 waves; wave w owns q-rows [t0+w*16, +16).
// q,k,gate,o layout [(b*2048+pos)*2048 + h*128 + d]; vT layout [b][h*128+d][t].
__global__ __launch_bounds__(512, 4) void k_attn(const bf16_t* __restrict__ q,
                                                 const bf16_t* __restrict__ k,
                                                 const bf16_t* __restrict__ vT,
                                                 const bf16_t* __restrict__ gate,
                                                 bf16_t* __restrict__ o) {
    __shared__ bf16_t Ks[64 * 136];   // [s][128 d +8]   17.4 KB
    __shared__ bf16_t Vt[128 * 72];   // [d][64 s +8]    18.4 KB
    __shared__ bf16_t Ps[128 * 72];   // [t][64 s +8]    18.4 KB
    const int qb = (int)gridDim.x - 1 - (int)blockIdx.x;  // long blocks first
    const int bh = blockIdx.y;
    const int b = bh >> 4, h = bh & 15;
    const int t0 = qb * 128;
    const int tid = threadIdx.x, lane = tid & 63, wv = tid >> 6;  // wv 0..7
    const int quad = lane >> 4, l16 = lane & 15;
    const int wrow = t0 + wv * 16;  // wave's first q row

    // Q fragments in registers (A-layout: m=l16, k=quad*8+j)
    bf16x8 aq[4];
    {
        const bf16_t* qp = q + ((size_t)(b * 2048 + wrow + l16)) * 2048 + h * 128 + quad * 8;
#pragma unroll
        for (int kk = 0; kk < 4; ++kk) aq[kk] = *(const bf16x8*)(qp + kk * 32);
    }
    f32x4 oacc[8] = {};
    float l_i[4] = {0.f, 0.f, 0.f, 0.f};

    const bf16_t* vbase = vT + ((size_t)b * 2048 + (size_t)h * 128) * 2048;
    const bf16_t* kbase = k + ((size_t)b * 2048) * 2048 + h * 128;

    // staging indices (512 threads)
    const int krow = tid >> 4;         // 0..31 (+32)
    const int kcol = (tid & 15) * 8;
    const int vrow = tid >> 3;         // 0..63 (+64)
    const int vcol = (tid & 7) * 8;

    const int nkb = 2 * qb + 2;  // key tiles 0 .. 2qb+1
    bf16x8 kreg0, kreg1, vreg0, vreg1;
    {
        kreg0 = *(const bf16x8*)(kbase + (size_t)krow * 2048 + kcol);
        kreg1 = *(const bf16x8*)(kbase + (size_t)(krow + 32) * 2048 + kcol);
        vreg0 = *(const bf16x8*)(vbase + (size_t)vrow * 2048 + vcol);
        vreg1 = *(const bf16x8*)(vbase + (size_t)(vrow + 64) * 2048 + vcol);
    }
    for (int kb = 0; kb < nkb; ++kb) {
        const int s0 = kb * 64;
        __syncthreads();  // prev iter done reading LDS
        *(bf16x8*)(Ks + krow * 136 + kcol) = kreg0;
        *(bf16x8*)(Ks + (krow + 32) * 136 + kcol) = kreg1;
        *(bf16x8*)(Vt + vrow * 72 + vcol) = vreg0;
        *(bf16x8*)(Vt + (vrow + 64) * 72 + vcol) = vreg1;
        __syncthreads();
        if (kb + 1 < nkb) {  // prefetch next tile; latency overlaps compute below
            const int sn = s0 + 64;
            kreg0 = *(const bf16x8*)(kbase + (size_t)(sn + krow) * 2048 + kcol);
            kreg1 = *(const bf16x8*)(kbase + (size_t)(sn + krow + 32) * 2048 + kcol);
            vreg0 = *(const bf16x8*)(vbase + (size_t)vrow * 2048 + sn + vcol);
            vreg1 = *(const bf16x8*)(vbase + (size_t)(vrow + 64) * 2048 + sn + vcol);
        }
        if (s0 > wrow + 15) continue;  // wave fully above diagonal (wave-uniform skip)
        // S = Q K^T : wave's 16x64 strip
        f32x4 sc[4] = {};
#pragma unroll
        for (int kk = 0; kk < 4; ++kk)
#pragma unroll
            for (int ni = 0; ni < 4; ++ni) {
                bf16x8 bk = *(bf16x8*)(Ks + (ni * 16 + l16) * 136 + kk * 32 + quad * 8);
                sc[ni] = __builtin_amdgcn_mfma_f32_16x16x32_bf16(aq[kk], bk, sc[ni], 0, 0, 0);
            }
        // fixed-max softmax: p = exp(s*SCALE - SMAX); no per-iter reductions
        const bool diag = (s0 + 63 > wrow);
        const int trowb = wrow + quad * 4;
#pragma unroll
        for (int ni = 0; ni < 4; ++ni) {
            int scol = s0 + ni * 16 + l16;
#pragma unroll
            for (int r2 = 0; r2 < 4; ++r2) {
                float pv = __expf(sc[ni][r2] * SCALE_F - SMAX_F);
                if (diag && scol > trowb + r2) pv = 0.f;
                sc[ni][r2] = pv;
                l_i[r2] += pv;
            }
        }
        // P: C-layout -> LDS -> A-layout (wave-private rows)
#pragma unroll
        for (int ni = 0; ni < 4; ++ni)
#pragma unroll
            for (int r2 = 0; r2 < 4; ++r2)
                Ps[(wv * 16 + quad * 4 + r2) * 72 + ni * 16 + l16] = (bf16_t)sc[ni][r2];
        // O += P V
#pragma unroll
        for (int kk = 0; kk < 2; ++kk) {
            bf16x8 ap = *(bf16x8*)(Ps + (wv * 16 + l16) * 72 + kk * 32 + quad * 8);
#pragma unroll
            for (int ni = 0; ni < 8; ++ni) {
                bf16x8 bv = *(bf16x8*)(Vt + (ni * 16 + l16) * 72 + kk * 32 + quad * 8);
                oacc[ni] = __builtin_amdgcn_mfma_f32_16x16x32_bf16(ap, bv, oacc[ni], 0, 0, 0);
            }
        }
    }
    // one final reduce of l over the 16 lanes holding each row
#pragma unroll
    for (int m = 8; m; m >>= 1)
#pragma unroll
        for (int r2 = 0; r2 < 4; ++r2) l_i[r2] += __shfl_xor(l_i[r2], m);
    // epilogue: normalize, silu(gate), store
    float rl[4];
#pragma unroll
    for (int r2 = 0; r2 < 4; ++r2) rl[r2] = 1.f / l_i[r2];
#pragma unroll
    for (int ni = 0; ni < 8; ++ni) {
        int d = ni * 16 + l16;
#pragma unroll
        for (int r2 = 0; r2 < 4; ++r2) {
            int trow = wrow + quad * 4 + r2;
            size_t gi = ((size_t)(b * 2048 + trow)) * 2048 + h * 128 + d;
            float gt = (float)gate[gi];
            float sg = gt / (1.f + __expf(-gt));
            o[gi] = (bf16_t)((oacc[ni][r2] * rl[r2]) * sg);
        }
    }
}

extern "C" void kernel_launch(void* const* d_in, const int* in_sizes, int n_in,
                              void* d_out, int out_size, void* d_ws, size_t ws_size,
                              hipStream_t stream) {
    const float* x         = (const float*)d_in[0];
    const float* w_q_down  = (const float*)d_in[1];
    const float* g_q_down  = (const float*)d_in[2];
    const float* w_q_up    = (const float*)d_in[3];
    const float* w_kv_down = (const float*)d_in[4];
    const float* g_kv_down = (const float*)d_in[5];
    const float* w_k_up    = (const float*)d_in[6];
    const float* w_v_up    = (const float*)d_in[7];
    const float* w_k_rope  = (const float*)d_in[8];
    const float* g_q       = (const float*)d_in[9];
    const float* g_k       = (const float*)d_in[10];
    const float* w_gate    = (const float*)d_in[11];
    const float* w_o       = (const float*)d_in[12];
    float* out = (float*)d_out;

    char* base = (char*)d_ws;
    size_t off = 0;
    auto alloc = [&](size_t bytes) -> void* {
        void* p = base + off;
        off = (off + bytes + 255) & ~(size_t)255;
        return p;
    };
    const size_t MT = 8192;  // B*T
    bf16_t* xb     = (bf16_t*)alloc(MT * 2048 * 2);
    bf16_t* wqd_t  = (bf16_t*)alloc((size_t)1024 * 2048 * 2);
    bf16_t* wqu_t  = (bf16_t*)alloc((size_t)2048 * 1024 * 2);
    bf16_t* wkvd_t = (bf16_t*)alloc((size_t)512 * 2048 * 2);
    bf16_t* wku_t  = (bf16_t*)alloc((size_t)1024 * 512 * 2);
    bf16_t* wvu_t  = (bf16_t*)alloc((size_t)2048 * 512 * 2);
    bf16_t* wkr_t  = (bf16_t*)alloc((size_t)64 * 2048 * 2);
    bf16_t* wg_t   = (bf16_t*)alloc((size_t)2048 * 2048 * 2);
    bf16_t* wo_t   = (bf16_t*)alloc((size_t)2048 * 2048 * 2);
    bf16_t* qc     = (bf16_t*)alloc(MT * 1024 * 2);
    bf16_t* ckv    = (bf16_t*)alloc(MT * 512 * 2);
    bf16_t* krope  = (bf16_t*)alloc(MT * 64 * 2);
    bf16_t* vT     = (bf16_t*)alloc(MT * 2048 * 2);  // [b][h*128+d][t]
    bf16_t* gbuf   = (bf16_t*)alloc(MT * 2048 * 2);
    float* cosT    = (float*)alloc((size_t)2048 * 64 * 4);
    float* sinT    = (float*)alloc((size_t)2048 * 64 * 4);
    bf16_t* knope = qc;              // qc dead after q_up GEMM
    bf16_t* qbuf  = (bf16_t*)d_out;  // d_out scratch until final GEMM
    bf16_t* kbuf  = (bf16_t*)d_out + MT * 2048;
    bf16_t* obuf  = xb;              // xb dead after all x@W GEMMs

    k_convert<<<dim3(16384), dim3(256), 0, stream>>>(x, xb, 16777216);
    k_transpose<<<dim3(32, 64), 256, 0, stream>>>(w_q_down, wqd_t, 2048, 1024);
    k_transpose<<<dim3(64, 32), 256, 0, stream>>>(w_q_up, wqu_t, 1024, 2048);
    k_transpose<<<dim3(16, 64), 256, 0, stream>>>(w_kv_down, wkvd_t, 2048, 512);
    k_transpose<<<dim3(32, 16), 256, 0, stream>>>(w_k_up, wku_t, 512, 1024);
    k_transpose<<<dim3(64, 16), 256, 0, stream>>>(w_v_up, wvu_t, 512, 2048);
    k_transpose<<<dim3(2, 64), 256, 0, stream>>>(w_k_rope, wkr_t, 2048, 64);
    k_transpose<<<dim3(64, 64), 256, 0, stream>>>(w_gate, wg_t, 2048, 2048);
    k_transpose<<<dim3(64, 64), 256, 0, stream>>>(w_o, wo_t, 2048, 2048);
    k_rope_tables<<<dim3(512), 256, 0, stream>>>(cosT, sinT);
    // q path
    k_gemm<0><<<dim3(8, 64), 256, 0, stream>>>(xb, wqd_t, qc, 8192, 1024, 2048, 0, 0, 0);
    k_rmsnorm<<<dim3(8192), 256, 0, stream>>>(qc, g_q_down, 1024);
    k_gemm<0><<<dim3(16, 64), 256, 0, stream>>>(qc, wqu_t, qbuf, 8192, 2048, 1024, 0, 0, 0);
    // kv path
    k_gemm<0><<<dim3(4, 64), 256, 0, stream>>>(xb, wkvd_t, ckv, 8192, 512, 2048, 0, 0, 0);
    k_rmsnorm<<<dim3(8192), 256, 0, stream>>>(ckv, g_kv_down, 512);
    k_gemm<0><<<dim3(8, 64), 256, 0, stream>>>(ckv, wku_t, knope, 8192, 1024, 512, 0, 0, 0);
    // V^T per batch: vT_b[hd][t] = wvu_t[hd][k] · ckv_b[t][k]
    k_gemm<0><<<dim3(16, 16, 4), 256, 0, stream>>>(wvu_t, ckv, vT, 2048, 2048, 512,
                                                   0, (size_t)2048 * 512, (size_t)2048 * 2048);
    k_gemm<0><<<dim3(1, 64), 256, 0, stream>>>(xb, wkr_t, krope, 8192, 64, 2048, 0, 0, 0);
    // gate
    k_gemm<0><<<dim3(16, 64), 256, 0, stream>>>(xb, wg_t, gbuf, 8192, 2048, 2048, 0, 0, 0);
    // assemble q/k
    k_build_q<<<dim3(32768), 256, 0, stream>>>(qbuf, g_q, cosT, sinT);
    k_build_k<<<dim3(32768), 256, 0, stream>>>(knope, krope, kbuf, g_k, cosT, sinT);
    // attention + silu(gate)
    k_attn<<<dim3(16, 64), 512, 0, stream>>>(qbuf, kbuf, vT, gbuf, obuf);
    // output projection
    k_gemm<1><<<dim3(16, 64), 256, 0, stream>>>(obuf, wo_t, out, 8192, 2048, 2048, 0, 0, 0);
}